// Round 6
// baseline (213.331 us; speedup 1.0000x reference)
//
#include <hip/hip_runtime.h>
#include <hip/hip_bf16.h>

#define N_ 4
#define L_ 1024
#define E_ 1024
#define H_ 32
#define HD_ 32

typedef unsigned short ushort;
typedef __attribute__((ext_vector_type(8))) short short8;   // bf16 x8 MFMA A/B frag
typedef __attribute__((ext_vector_type(4))) float float4v;  // MFMA C/D frag
typedef __attribute__((ext_vector_type(2))) unsigned int uint2v;
typedef __attribute__((ext_vector_type(2))) float float2v;

// branch-free RNE f32->bf16 (finite inputs)
__device__ __forceinline__ unsigned packbf2(float a, float b) {
    unsigned ua = __float_as_uint(a);
    unsigned ub = __float_as_uint(b);
    ua += 0x7FFFu + ((ua >> 16) & 1u);
    ub += 0x7FFFu + ((ub >> 16) & 1u);
    return (ua >> 16) | (ub & 0xFFFF0000u);
}

__device__ __forceinline__ ushort f2b(float f) {
    unsigned u = __float_as_uint(f);
    u += 0x7FFFu + ((u >> 16) & 1u);
    return (ushort)(u >> 16);
}

__device__ __forceinline__ float fast_exp2(float x) {
#if __has_builtin(__builtin_amdgcn_exp2f)
    return __builtin_amdgcn_exp2f(x);        // raw v_exp_f32 (2^x)
#else
    return __expf(x * 0.69314718056f);
#endif
}

// load 8 consecutive fp32, convert to bf16x8 frag (RNE)
__device__ __forceinline__ short8 cvt8(const float* __restrict__ p) {
    float4v a = *(const float4v*)p;
    float4v b = *(const float4v*)(p + 4);
    union { unsigned u[4]; short8 s; } r;
    r.u[0] = packbf2(a[0], a[1]); r.u[1] = packbf2(a[2], a[3]);
    r.u[2] = packbf2(b[0], b[1]); r.u[3] = packbf2(b[2], b[3]);
    return r.s;
}

// ---------------------------------------------------------------------------
// Kernel 1: per-head projections via MFMA, no LDS.  UNCHANGED (control).
// grid (L/64, H, N), block 256.
// ---------------------------------------------------------------------------
__global__ __launch_bounds__(256) void proj_kernel(
    const float* __restrict__ v_in, const float* __restrict__ k_in,
    const float* __restrict__ q_in,
    const float* __restrict__ Wv, const float* __restrict__ Wk,
    const float* __restrict__ Wq, const float* __restrict__ Wo,
    const int* __restrict__ mask,
    ushort* __restrict__ vt_ws, ushort* __restrict__ k_ws,
    ushort* __restrict__ q_ws, ushort* __restrict__ wo_bf,
    float* __restrict__ bias_f)
{
    const int n = blockIdx.z, h = blockIdx.y, l0 = blockIdx.x * 64;
    const int t = threadIdx.x, wave = t >> 6, lane = t & 63;
    const int m = lane & 15, g = lane >> 4;

    // Wo -> bf16: linear block id covers 1Mi elements, 2 per thread
    {
        const int lb = ((n * H_ + h) << 4) + blockIdx.x;   // 0..2047
        const int i = lb * 256 + t;                        // dword index
        float2v w2 = *(const float2v*)(Wo + 2 * i);
        ((unsigned*)wo_bf)[i] = packbf2(w2[0], w2[1]);
    }
    // mask -> additive bias, done once (h==0 slice)
    if (h == 0 && t < 64)
        bias_f[n * L_ + l0 + t] = (mask[n * L_ + l0 + t] == 0) ? -1e30f : 0.0f;

    const size_t row = (size_t)(n * L_) + l0 + wave * 16 + m;
    const float* src[3] = {v_in, k_in, q_in};
    const float* wsrc[3] = {Wv, Wk, Wq};

    short8 Xf[3], Wf[3][2];
#pragma unroll
    for (int mat = 0; mat < 3; ++mat) {
        Xf[mat] = cvt8(src[mat] + row * E_ + h * HD_ + g * 8);
#pragma unroll
        for (int dt = 0; dt < 2; ++dt)
            Wf[mat][dt] = cvt8(wsrc[mat] + (dt * 16 + m) * HD_ + g * 8);
    }

    const size_t obase = (size_t)(n * H_ + h) * L_;
    const size_t vb = (size_t)(n * H_ + h) * HD_ * L_;
    const int tok = l0 + wave * 16 + m;   // this lane's token (D col = m)

    // q,k: D[d][tok]; lane's 4 accs are consecutive d -> one 8B store per dt
#pragma unroll
    for (int mat = 1; mat < 3; ++mat) {
        ushort* outp = (mat == 1) ? k_ws : q_ws;
#pragma unroll
        for (int dt = 0; dt < 2; ++dt) {
            float4v z = float4v{0.f, 0.f, 0.f, 0.f};
            float4v acc = __builtin_amdgcn_mfma_f32_16x16x32_bf16(Wf[mat][dt], Xf[mat], z, 0, 0, 0);
            uint2v pk;
            pk[0] = packbf2(acc[0], acc[1]);
            pk[1] = packbf2(acc[2], acc[3]);
            *(uint2v*)(outp + (obase + tok) * HD_ + dt * 16 + g * 4) = pk;
        }
    }
    // v: D[d][tok] -> vt[d][tok], lane m = tok (coalesced 32B runs)
#pragma unroll
    for (int dt = 0; dt < 2; ++dt) {
        float4v z = float4v{0.f, 0.f, 0.f, 0.f};
        float4v acc = __builtin_amdgcn_mfma_f32_16x16x32_bf16(Wf[0][dt], Xf[0], z, 0, 0, 0);
#pragma unroll
        for (int r = 0; r < 4; ++r) {
            int d = dt * 16 + g * 4 + r;
            vt_ws[vb + (size_t)d * L_ + tok] = f2b(acc[r]);
        }
    }
}

// ---------------------------------------------------------------------------
// Kernel 2: attention — round-5 pipeline + sched_barrier(0) PIN.
// Diagnosis r5: compiler sank all prefetches to use sites (VGPR_Count=64
// proves it: the pipeline needs ~114 live regs) -> lockstep stall, 46% of
// cycles nothing issues.  Grid-limited occupancy means 128 VGPR is free.
// Fix: __builtin_amdgcn_sched_barrier(0) right after the kf(c+1)/vf(c)
// prefetch pair -> loads cannot sink below, softmax_b cannot hoist above;
// compiler's own waitcnt insertion then emits counted waits (vmcnt(4)
// before S_a, drain before PV_a) with a full softmax phase of cover.
// grid 1024 blocks, block 256, launch_bounds(256,4) -> 128-VGPR cap.
// ---------------------------------------------------------------------------
__global__ __launch_bounds__(256, 4) void attn_kernel(
    const ushort* __restrict__ q_ws, const ushort* __restrict__ k_ws,
    const ushort* __restrict__ vt_ws, const float* __restrict__ bias_f,
    ushort* __restrict__ x_ws)
{
    const int B = blockIdx.x;
    const int head = ((B >> 6) << 3) + (B & 7);
    const int qt = (B >> 3) & 7;
    const int n = head >> 5, h = head & 31, q0 = qt * 128;

    const int t = threadIdx.x, wave = t >> 6, lane = t & 63;
    const int m = lane & 15, g = lane >> 4;

    __shared__ ushort sP[4][2][2][16][72];   // [wave][buf][tile][q][tok]

    const size_t base = (size_t)(n * H_ + h) * L_;
    const ushort* vb_p = vt_ws + (size_t)(n * H_ + h) * HD_ * L_;

    short8 qfa = *(const short8*)(q_ws + (base + q0 + wave * 16 + m) * HD_ + g * 8);
    short8 qfb = *(const short8*)(q_ws + (base + q0 + 64 + wave * 16 + m) * HD_ + g * 8);

    float4v Oa[2], Ob[2];
    Oa[0] = float4v{0.f,0.f,0.f,0.f}; Oa[1] = float4v{0.f,0.f,0.f,0.f};
    Ob[0] = float4v{0.f,0.f,0.f,0.f}; Ob[1] = float4v{0.f,0.f,0.f,0.f};
    float rsa[4] = {0.f,0.f,0.f,0.f}, rsb[4] = {0.f,0.f,0.f,0.f};
    const float k1 = 0.03125f * 1.44269504f;

    ushort* const pa0 = &sP[wave][0][0][m][0];
    ushort* const pa1 = &sP[wave][1][0][m][0];
    ushort* const pb0 = &sP[wave][0][1][m][0];
    ushort* const pb1 = &sP[wave][1][1][m][0];

    const ushort* kp = k_ws + base * HD_ + (size_t)m * HD_ + g * 8;
    const ushort* vp = vb_p + (size_t)m * L_ + g * 8;
    const float*  bp = bias_f + n * L_ + g * 4;

    // ---- prologue: chunk 0 ----
    short8 kf[4];
#pragma unroll
    for (int nb = 0; nb < 4; ++nb)
        kf[nb] = *(const short8*)(kp + (size_t)nb * 16 * HD_);
    kp += (size_t)64 * HD_;

    float4v b4[4];
#pragma unroll
    for (int nb = 0; nb < 4; ++nb)
        b4[nb] = *(const float4v*)(bp + nb * 16);
    bp += 64;

    float4v Sa[4], Sb[4];
#pragma unroll
    for (int nb = 0; nb < 4; ++nb) {
        float4v z = float4v{0.f,0.f,0.f,0.f};
        Sa[nb] = __builtin_amdgcn_mfma_f32_16x16x32_bf16(kf[nb], qfa, z, 0, 0, 0);
        Sb[nb] = __builtin_amdgcn_mfma_f32_16x16x32_bf16(kf[nb], qfb, z, 0, 0, 0);
    }
    // prefetch K chunk 1 (after both S issues; WAR clear)
#pragma unroll
    for (int nb = 0; nb < 4; ++nb)
        kf[nb] = *(const short8*)(kp + (size_t)nb * 16 * HD_);
    kp += (size_t)64 * HD_;
    // prefetch V chunk 0
    short8 vf[2][2];
#pragma unroll
    for (int kb = 0; kb < 2; ++kb)
#pragma unroll
        for (int db = 0; db < 2; ++db)
            vf[kb][db] = *(const short8*)(vp + (size_t)db * 16 * L_ + kb * 32);
    vp += 64;
    // PIN: prefetches stay above, softmax below
    __builtin_amdgcn_sched_barrier(0);

#pragma unroll
    for (int nb = 0; nb < 4; ++nb) {
        float a0 = fast_exp2(fmaf(Sa[nb][0], k1, b4[nb][0]));
        float a1 = fast_exp2(fmaf(Sa[nb][1], k1, b4[nb][1]));
        float a2 = fast_exp2(fmaf(Sa[nb][2], k1, b4[nb][2]));
        float a3 = fast_exp2(fmaf(Sa[nb][3], k1, b4[nb][3]));
        rsa[0] += a0; rsa[1] += a1; rsa[2] += a2; rsa[3] += a3;
        uint2v pk; pk[0] = packbf2(a0, a1); pk[1] = packbf2(a2, a3);
        *(uint2v*)(pa0 + nb * 16 + g * 4) = pk;
        float e0 = fast_exp2(fmaf(Sb[nb][0], k1, b4[nb][0]));
        float e1 = fast_exp2(fmaf(Sb[nb][1], k1, b4[nb][1]));
        float e2 = fast_exp2(fmaf(Sb[nb][2], k1, b4[nb][2]));
        float e3 = fast_exp2(fmaf(Sb[nb][3], k1, b4[nb][3]));
        rsb[0] += e0; rsb[1] += e1; rsb[2] += e2; rsb[3] += e3;
        uint2v qk; qk[0] = packbf2(e0, e1); qk[1] = packbf2(e2, e3);
        *(uint2v*)(pb0 + nb * 16 + g * 4) = qk;
    }

    // ---- main loop ----
    for (int c = 1; c < 16; ++c) {
        // bias for chunk c
#pragma unroll
        for (int nb = 0; nb < 4; ++nb)
            b4[nb] = *(const float4v*)(bp + nb * 16);
        bp += 64;

        // S_a(c): kf resident since last chunk's prefetch
#pragma unroll
        for (int nb = 0; nb < 4; ++nb) {
            float4v z = float4v{0.f,0.f,0.f,0.f};
            Sa[nb] = __builtin_amdgcn_mfma_f32_16x16x32_bf16(kf[nb], qfa, z, 0, 0, 0);
        }

        // PV_a(c-1): vf resident since last chunk's prefetch
        const ushort* ra = (c & 1) ? pa0 : pa1;
#pragma unroll
        for (int kb = 0; kb < 2; ++kb) {
            short8 af = *(const short8*)(ra + kb * 32 + g * 8);
            Oa[0] = __builtin_amdgcn_mfma_f32_16x16x32_bf16(af, vf[kb][0], Oa[0], 0, 0, 0);
            Oa[1] = __builtin_amdgcn_mfma_f32_16x16x32_bf16(af, vf[kb][1], Oa[1], 0, 0, 0);
        }

        // softmax_a(c)
        ushort* wa = (c & 1) ? pa1 : pa0;
#pragma unroll
        for (int nb = 0; nb < 4; ++nb) {
            float a0 = fast_exp2(fmaf(Sa[nb][0], k1, b4[nb][0]));
            float a1 = fast_exp2(fmaf(Sa[nb][1], k1, b4[nb][1]));
            float a2 = fast_exp2(fmaf(Sa[nb][2], k1, b4[nb][2]));
            float a3 = fast_exp2(fmaf(Sa[nb][3], k1, b4[nb][3]));
            rsa[0] += a0; rsa[1] += a1; rsa[2] += a2; rsa[3] += a3;
            uint2v pk; pk[0] = packbf2(a0, a1); pk[1] = packbf2(a2, a3);
            *(uint2v*)(wa + nb * 16 + g * 4) = pk;
        }

        // S_b(c): last consumer of kf(c)
#pragma unroll
        for (int nb = 0; nb < 4; ++nb) {
            float4v z = float4v{0.f,0.f,0.f,0.f};
            Sb[nb] = __builtin_amdgcn_mfma_f32_16x16x32_bf16(kf[nb], qfb, z, 0, 0, 0);
        }
        // prefetch K chunk c+1 (WAR clear: S_b issued; at c=15 reads past
        // k_ws into vt_ws -> in-workspace, never consumed)
#pragma unroll
        for (int nb = 0; nb < 4; ++nb)
            kf[nb] = *(const short8*)(kp + (size_t)nb * 16 * HD_);
        kp += (size_t)64 * HD_;

        // PV_b(c-1): last consumer of vf(c-1)
        const ushort* rb = (c & 1) ? pb0 : pb1;
#pragma unroll
        for (int kb = 0; kb < 2; ++kb) {
            short8 bf = *(const short8*)(rb + kb * 32 + g * 8);
            Ob[0] = __builtin_amdgcn_mfma_f32_16x16x32_bf16(bf, vf[kb][0], Ob[0], 0, 0, 0);
            Ob[1] = __builtin_amdgcn_mfma_f32_16x16x32_bf16(bf, vf[kb][1], Ob[1], 0, 0, 0);
        }
        // prefetch V chunk c (WAR clear: both PVs issued)
#pragma unroll
        for (int kb = 0; kb < 2; ++kb)
#pragma unroll
            for (int db = 0; db < 2; ++db)
                vf[kb][db] = *(const short8*)(vp + (size_t)db * 16 * L_ + kb * 32);
        vp += 64;

        // PIN: kf/vf prefetches cannot sink below this point; softmax_b
        // cannot hoist above.  Loads keep the whole softmax_b phase of
        // cover and registers stay live across it (needs >64 VGPR, which
        // is free: occupancy is grid-limited at 4 waves/SIMD).
        __builtin_amdgcn_sched_barrier(0);

        // softmax_b(c)
        ushort* wb = (c & 1) ? pb1 : pb0;
#pragma unroll
        for (int nb = 0; nb < 4; ++nb) {
            float e0 = fast_exp2(fmaf(Sb[nb][0], k1, b4[nb][0]));
            float e1 = fast_exp2(fmaf(Sb[nb][1], k1, b4[nb][1]));
            float e2 = fast_exp2(fmaf(Sb[nb][2], k1, b4[nb][2]));
            float e3 = fast_exp2(fmaf(Sb[nb][3], k1, b4[nb][3]));
            rsb[0] += e0; rsb[1] += e1; rsb[2] += e2; rsb[3] += e3;
            uint2v qk; qk[0] = packbf2(e0, e1); qk[1] = packbf2(e2, e3);
            *(uint2v*)(wb + nb * 16 + g * 4) = qk;
        }
    }

    // ---- epilogue: PV(15) with resident vf; c=15 wrote buf1 ----
#pragma unroll
    for (int kb = 0; kb < 2; ++kb) {
        short8 af = *(const short8*)(pa1 + kb * 32 + g * 8);
        Oa[0] = __builtin_amdgcn_mfma_f32_16x16x32_bf16(af, vf[kb][0], Oa[0], 0, 0, 0);
        Oa[1] = __builtin_amdgcn_mfma_f32_16x16x32_bf16(af, vf[kb][1], Oa[1], 0, 0, 0);
    }
#pragma unroll
    for (int kb = 0; kb < 2; ++kb) {
        short8 bf = *(const short8*)(pb1 + kb * 32 + g * 8);
        Ob[0] = __builtin_amdgcn_mfma_f32_16x16x32_bf16(bf, vf[kb][0], Ob[0], 0, 0, 0);
        Ob[1] = __builtin_amdgcn_mfma_f32_16x16x32_bf16(bf, vf[kb][1], Ob[1], 0, 0, 0);
    }

    float ra = (rsa[0] + rsa[1]) + (rsa[2] + rsa[3]);
    float rb = (rsb[0] + rsb[1]) + (rsb[2] + rsb[3]);
    ra += __shfl_xor(ra, 16, 64); ra += __shfl_xor(ra, 32, 64);
    rb += __shfl_xor(rb, 16, 64); rb += __shfl_xor(rb, 32, 64);
#pragma unroll
    for (int r = 0; r < 4; ++r) {
        float inva = 1.f / __shfl(ra, g * 4 + r, 64);
        float invb = 1.f / __shfl(rb, g * 4 + r, 64);
        size_t rowa = (size_t)n * L_ + q0 + wave * 16 + g * 4 + r;
        size_t rowb = rowa + 64;
#pragma unroll
        for (int db = 0; db < 2; ++db) {
            x_ws[rowa * E_ + h * HD_ + db * 16 + m] = f2b(Oa[db][r] * inva);
            x_ws[rowb * E_ + h * HD_ + db * 16 + m] = f2b(Ob[db][r] * invb);
        }
    }
}

// ---------------------------------------------------------------------------
// Kernel 3: C = X(bf16) @ Wo^T(bf16, pre-converted by proj) + bo, fp32 out.
// UNCHANGED (control).  64x64 tile, BK=64, 1024 blocks, XCD-swizzled,
// register-prefetch pipeline.
// ---------------------------------------------------------------------------
__global__ __launch_bounds__(256) void out_gemm_kernel(
    const ushort* __restrict__ X, const ushort* __restrict__ wo_bf,
    const float* __restrict__ bo, float* __restrict__ C)
{
    const int B = blockIdx.x;
    const int it = ((B >> 7) << 3) + (B & 7);   // 0..63
    const int jt = (B >> 3) & 15;               // 0..15
    const int i0 = it * 64, j0 = jt * 64;

    const int t = threadIdx.x, wave = t >> 6, lane = t & 63;
    const int m = lane & 15, g = lane >> 4;

    __shared__ ushort sA[64][72];
    __shared__ ushort sB[64][72];

    float4v acc[4];
#pragma unroll
    for (int nb = 0; nb < 4; ++nb) acc[nb] = float4v{0.f,0.f,0.f,0.f};

    const int r0 = t >> 2;          // 0..63
    const int c0 = (t & 3) * 16;    // 0..48

    const ushort* xp = X + (size_t)(i0 + r0) * E_ + c0;
    const ushort* wp = wo_bf + (size_t)(j0 + r0) * E_ + c0;

    short8 xr0 = *(const short8*)xp;
    short8 xr1 = *(const short8*)(xp + 8);
    short8 wr0 = *(const short8*)wp;
    short8 wr1 = *(const short8*)(wp + 8);

    for (int k0 = 0; k0 < E_; k0 += 64) {
        __syncthreads();
        *(short8*)&sA[r0][c0]     = xr0;
        *(short8*)&sA[r0][c0 + 8] = xr1;
        *(short8*)&sB[r0][c0]     = wr0;
        *(short8*)&sB[r0][c0 + 8] = wr1;
        __syncthreads();
        if (k0 + 64 < E_) {   // uniform; prefetch next k-tile during compute
            xr0 = *(const short8*)(xp + k0 + 64);
            xr1 = *(const short8*)(xp + k0 + 72);
            wr0 = *(const short8*)(wp + k0 + 64);
            wr1 = *(const short8*)(wp + k0 + 72);
        }
#pragma unroll
        for (int kb = 0; kb < 2; ++kb) {
            short8 afr = *(const short8*)&sA[wave * 16 + m][kb * 32 + g * 8];
#pragma unroll
            for (int nb = 0; nb < 4; ++nb) {
                short8 bfr = *(const short8*)&sB[nb * 16 + m][kb * 32 + g * 8];
                acc[nb] = __builtin_amdgcn_mfma_f32_16x16x32_bf16(afr, bfr, acc[nb], 0, 0, 0);
            }
        }
    }

#pragma unroll
    for (int nb = 0; nb < 4; ++nb) {
        int col = j0 + nb * 16 + m;
        float bias = bo[col];
#pragma unroll
        for (int r = 0; r < 4; ++r) {
            int rowi = i0 + wave * 16 + g * 4 + r;
            C[(size_t)rowi * E_ + col] = acc[nb][r] + bias;
        }
    }
}

// ---------------------------------------------------------------------------
extern "C" void kernel_launch(void* const* d_in, const int* in_sizes, int n_in,
                              void* d_out, int out_size, void* d_ws, size_t ws_size,
                              hipStream_t stream) {
    const float* values = (const float*)d_in[0];
    const float* keys   = (const float*)d_in[1];
    const float* query  = (const float*)d_in[2];
    const int*   mask   = (const int*)d_in[3];
    const float* Wv     = (const float*)d_in[4];
    const float* Wk     = (const float*)d_in[5];
    const float* Wq     = (const float*)d_in[6];
    const float* Wo     = (const float*)d_in[7];
    const float* bo     = (const float*)d_in[8];
    float* out = (float*)d_out;

    const size_t M4 = (size_t)N_ * H_ * L_ * HD_;   // 4 Mi elements
    ushort* q_ws   = (ushort*)d_ws;
    ushort* k_ws   = q_ws + M4;
    ushort* vt_ws  = k_ws + M4;
    ushort* x_ws   = vt_ws + M4;
    ushort* wo_bf  = x_ws + M4;                     // 1 Mi ushort
    float*  bias_f = (float*)(wo_bf + (size_t)E_ * E_);  // 4096 floats

    proj_kernel<<<dim3(L_ / 64, H_, N_), 256, 0, stream>>>(
        values, keys, query, Wv, Wk, Wq, Wo, mask,
        vt_ws, k_ws, q_ws, wo_bf, bias_f);

    attn_kernel<<<dim3(1024), 256, 0, stream>>>(
        q_ws, k_ws, vt_ws, bias_f, x_ws);

    out_gemm_kernel<<<dim3(1024), 256, 0, stream>>>(
        x_ws, wo_bf, bo, out);
}

// Round 7
// 212.558 us; speedup vs baseline: 1.0036x; 1.0036x over previous
//
#include <hip/hip_runtime.h>
#include <hip/hip_bf16.h>

#define N_ 4
#define L_ 1024
#define E_ 1024
#define H_ 32
#define HD_ 32

typedef unsigned short ushort;
typedef __attribute__((ext_vector_type(8))) short short8;   // bf16 x8 MFMA A/B frag
typedef __attribute__((ext_vector_type(4))) float float4v;  // MFMA C/D frag
typedef __attribute__((ext_vector_type(2))) unsigned int uint2v;
typedef __attribute__((ext_vector_type(2))) float float2v;

// branch-free RNE f32->bf16 (finite inputs)
__device__ __forceinline__ unsigned packbf2(float a, float b) {
    unsigned ua = __float_as_uint(a);
    unsigned ub = __float_as_uint(b);
    ua += 0x7FFFu + ((ua >> 16) & 1u);
    ub += 0x7FFFu + ((ub >> 16) & 1u);
    return (ua >> 16) | (ub & 0xFFFF0000u);
}

__device__ __forceinline__ ushort f2b(float f) {
    unsigned u = __float_as_uint(f);
    u += 0x7FFFu + ((u >> 16) & 1u);
    return (ushort)(u >> 16);
}

__device__ __forceinline__ float fast_exp2(float x) {
#if __has_builtin(__builtin_amdgcn_exp2f)
    return __builtin_amdgcn_exp2f(x);        // raw v_exp_f32 (2^x)
#else
    return __expf(x * 0.69314718056f);
#endif
}

// load 8 consecutive fp32, convert to bf16x8 frag (RNE)
__device__ __forceinline__ short8 cvt8(const float* __restrict__ p) {
    float4v a = *(const float4v*)p;
    float4v b = *(const float4v*)(p + 4);
    union { unsigned u[4]; short8 s; } r;
    r.u[0] = packbf2(a[0], a[1]); r.u[1] = packbf2(a[2], a[3]);
    r.u[2] = packbf2(b[0], b[1]); r.u[3] = packbf2(b[2], b[3]);
    return r.s;
}

// ---------------------------------------------------------------------------
// Kernel 1: per-head projections via MFMA, no LDS.  UNCHANGED (control).
// grid (L/64, H, N), block 256.
// ---------------------------------------------------------------------------
__global__ __launch_bounds__(256) void proj_kernel(
    const float* __restrict__ v_in, const float* __restrict__ k_in,
    const float* __restrict__ q_in,
    const float* __restrict__ Wv, const float* __restrict__ Wk,
    const float* __restrict__ Wq, const float* __restrict__ Wo,
    const int* __restrict__ mask,
    ushort* __restrict__ vt_ws, ushort* __restrict__ k_ws,
    ushort* __restrict__ q_ws, ushort* __restrict__ wo_bf,
    float* __restrict__ bias_f)
{
    const int n = blockIdx.z, h = blockIdx.y, l0 = blockIdx.x * 64;
    const int t = threadIdx.x, wave = t >> 6, lane = t & 63;
    const int m = lane & 15, g = lane >> 4;

    // Wo -> bf16: linear block id covers 1Mi elements, 2 per thread
    {
        const int lb = ((n * H_ + h) << 4) + blockIdx.x;   // 0..2047
        const int i = lb * 256 + t;                        // dword index
        float2v w2 = *(const float2v*)(Wo + 2 * i);
        ((unsigned*)wo_bf)[i] = packbf2(w2[0], w2[1]);
    }
    // mask -> additive bias, done once (h==0 slice)
    if (h == 0 && t < 64)
        bias_f[n * L_ + l0 + t] = (mask[n * L_ + l0 + t] == 0) ? -1e30f : 0.0f;

    const size_t row = (size_t)(n * L_) + l0 + wave * 16 + m;
    const float* src[3] = {v_in, k_in, q_in};
    const float* wsrc[3] = {Wv, Wk, Wq};

    short8 Xf[3], Wf[3][2];
#pragma unroll
    for (int mat = 0; mat < 3; ++mat) {
        Xf[mat] = cvt8(src[mat] + row * E_ + h * HD_ + g * 8);
#pragma unroll
        for (int dt = 0; dt < 2; ++dt)
            Wf[mat][dt] = cvt8(wsrc[mat] + (dt * 16 + m) * HD_ + g * 8);
    }

    const size_t obase = (size_t)(n * H_ + h) * L_;
    const size_t vb = (size_t)(n * H_ + h) * HD_ * L_;
    const int tok = l0 + wave * 16 + m;   // this lane's token (D col = m)

    // q,k: D[d][tok]; lane's 4 accs are consecutive d -> one 8B store per dt
#pragma unroll
    for (int mat = 1; mat < 3; ++mat) {
        ushort* outp = (mat == 1) ? k_ws : q_ws;
#pragma unroll
        for (int dt = 0; dt < 2; ++dt) {
            float4v z = float4v{0.f, 0.f, 0.f, 0.f};
            float4v acc = __builtin_amdgcn_mfma_f32_16x16x32_bf16(Wf[mat][dt], Xf[mat], z, 0, 0, 0);
            uint2v pk;
            pk[0] = packbf2(acc[0], acc[1]);
            pk[1] = packbf2(acc[2], acc[3]);
            *(uint2v*)(outp + (obase + tok) * HD_ + dt * 16 + g * 4) = pk;
        }
    }
    // v: D[d][tok] -> vt[d][tok], lane m = tok (coalesced 32B runs)
#pragma unroll
    for (int dt = 0; dt < 2; ++dt) {
        float4v z = float4v{0.f, 0.f, 0.f, 0.f};
        float4v acc = __builtin_amdgcn_mfma_f32_16x16x32_bf16(Wf[0][dt], Xf[0], z, 0, 0, 0);
#pragma unroll
        for (int r = 0; r < 4; ++r) {
            int d = dt * 16 + g * 4 + r;
            vt_ws[vb + (size_t)d * L_ + tok] = f2b(acc[r]);
        }
    }
}

// ---------------------------------------------------------------------------
// Kernel 2: attention — round-6 pipeline+pin, PLUS amdgpu_waves_per_eu(4,4).
// Diagnosis r6: the pin held the schedule but the allocator still targeted
// 8 waves/EU (default), chose VGPR=64, and SPILLED the pinned prefetches
// (WRITE_SIZE 8192->26624 KB = scratch).  launch_bounds' 2nd arg only sets
// the MIN waves/EU (a reg ceiling); the occupancy TARGET stayed 8.
// waves_per_eu(4,4) clamps min=max=4 -> allocator has no reason to shrink
// below 128 regs; the ~110-reg pipeline fits with zero spills.  Grid is
// 4 blocks/CU so 4 waves/SIMD is already the occupancy cap - nothing lost.
// grid 1024 blocks, block 256.
// ---------------------------------------------------------------------------
__global__ __launch_bounds__(256)
__attribute__((amdgpu_waves_per_eu(4, 4)))
void attn_kernel(
    const ushort* __restrict__ q_ws, const ushort* __restrict__ k_ws,
    const ushort* __restrict__ vt_ws, const float* __restrict__ bias_f,
    ushort* __restrict__ x_ws)
{
    const int B = blockIdx.x;
    const int head = ((B >> 6) << 3) + (B & 7);
    const int qt = (B >> 3) & 7;
    const int n = head >> 5, h = head & 31, q0 = qt * 128;

    const int t = threadIdx.x, wave = t >> 6, lane = t & 63;
    const int m = lane & 15, g = lane >> 4;

    __shared__ ushort sP[4][2][2][16][72];   // [wave][buf][tile][q][tok]

    const size_t base = (size_t)(n * H_ + h) * L_;
    const ushort* vb_p = vt_ws + (size_t)(n * H_ + h) * HD_ * L_;

    short8 qfa = *(const short8*)(q_ws + (base + q0 + wave * 16 + m) * HD_ + g * 8);
    short8 qfb = *(const short8*)(q_ws + (base + q0 + 64 + wave * 16 + m) * HD_ + g * 8);

    float4v Oa[2], Ob[2];
    Oa[0] = float4v{0.f,0.f,0.f,0.f}; Oa[1] = float4v{0.f,0.f,0.f,0.f};
    Ob[0] = float4v{0.f,0.f,0.f,0.f}; Ob[1] = float4v{0.f,0.f,0.f,0.f};
    float rsa[4] = {0.f,0.f,0.f,0.f}, rsb[4] = {0.f,0.f,0.f,0.f};
    const float k1 = 0.03125f * 1.44269504f;

    ushort* const pa0 = &sP[wave][0][0][m][0];
    ushort* const pa1 = &sP[wave][1][0][m][0];
    ushort* const pb0 = &sP[wave][0][1][m][0];
    ushort* const pb1 = &sP[wave][1][1][m][0];

    const ushort* kp = k_ws + base * HD_ + (size_t)m * HD_ + g * 8;
    const ushort* vp = vb_p + (size_t)m * L_ + g * 8;
    const float*  bp = bias_f + n * L_ + g * 4;

    // ---- prologue: chunk 0 ----
    short8 kf[4];
#pragma unroll
    for (int nb = 0; nb < 4; ++nb)
        kf[nb] = *(const short8*)(kp + (size_t)nb * 16 * HD_);
    kp += (size_t)64 * HD_;

    float4v b4[4];
#pragma unroll
    for (int nb = 0; nb < 4; ++nb)
        b4[nb] = *(const float4v*)(bp + nb * 16);
    bp += 64;

    float4v Sa[4], Sb[4];
#pragma unroll
    for (int nb = 0; nb < 4; ++nb) {
        float4v z = float4v{0.f,0.f,0.f,0.f};
        Sa[nb] = __builtin_amdgcn_mfma_f32_16x16x32_bf16(kf[nb], qfa, z, 0, 0, 0);
        Sb[nb] = __builtin_amdgcn_mfma_f32_16x16x32_bf16(kf[nb], qfb, z, 0, 0, 0);
    }
    // prefetch K chunk 1 (after both S issues; WAR clear)
#pragma unroll
    for (int nb = 0; nb < 4; ++nb)
        kf[nb] = *(const short8*)(kp + (size_t)nb * 16 * HD_);
    kp += (size_t)64 * HD_;
    // prefetch V chunk 0
    short8 vf[2][2];
#pragma unroll
    for (int kb = 0; kb < 2; ++kb)
#pragma unroll
        for (int db = 0; db < 2; ++db)
            vf[kb][db] = *(const short8*)(vp + (size_t)db * 16 * L_ + kb * 32);
    vp += 64;
    // PIN: prefetches stay above, softmax below
    __builtin_amdgcn_sched_barrier(0);

#pragma unroll
    for (int nb = 0; nb < 4; ++nb) {
        float a0 = fast_exp2(fmaf(Sa[nb][0], k1, b4[nb][0]));
        float a1 = fast_exp2(fmaf(Sa[nb][1], k1, b4[nb][1]));
        float a2 = fast_exp2(fmaf(Sa[nb][2], k1, b4[nb][2]));
        float a3 = fast_exp2(fmaf(Sa[nb][3], k1, b4[nb][3]));
        rsa[0] += a0; rsa[1] += a1; rsa[2] += a2; rsa[3] += a3;
        uint2v pk; pk[0] = packbf2(a0, a1); pk[1] = packbf2(a2, a3);
        *(uint2v*)(pa0 + nb * 16 + g * 4) = pk;
        float e0 = fast_exp2(fmaf(Sb[nb][0], k1, b4[nb][0]));
        float e1 = fast_exp2(fmaf(Sb[nb][1], k1, b4[nb][1]));
        float e2 = fast_exp2(fmaf(Sb[nb][2], k1, b4[nb][2]));
        float e3 = fast_exp2(fmaf(Sb[nb][3], k1, b4[nb][3]));
        rsb[0] += e0; rsb[1] += e1; rsb[2] += e2; rsb[3] += e3;
        uint2v qk; qk[0] = packbf2(e0, e1); qk[1] = packbf2(e2, e3);
        *(uint2v*)(pb0 + nb * 16 + g * 4) = qk;
    }

    // ---- main loop ----
    for (int c = 1; c < 16; ++c) {
        // bias for chunk c
#pragma unroll
        for (int nb = 0; nb < 4; ++nb)
            b4[nb] = *(const float4v*)(bp + nb * 16);
        bp += 64;

        // S_a(c): kf resident since last chunk's prefetch
#pragma unroll
        for (int nb = 0; nb < 4; ++nb) {
            float4v z = float4v{0.f,0.f,0.f,0.f};
            Sa[nb] = __builtin_amdgcn_mfma_f32_16x16x32_bf16(kf[nb], qfa, z, 0, 0, 0);
        }

        // PV_a(c-1): vf resident since last chunk's prefetch
        const ushort* ra = (c & 1) ? pa0 : pa1;
#pragma unroll
        for (int kb = 0; kb < 2; ++kb) {
            short8 af = *(const short8*)(ra + kb * 32 + g * 8);
            Oa[0] = __builtin_amdgcn_mfma_f32_16x16x32_bf16(af, vf[kb][0], Oa[0], 0, 0, 0);
            Oa[1] = __builtin_amdgcn_mfma_f32_16x16x32_bf16(af, vf[kb][1], Oa[1], 0, 0, 0);
        }

        // softmax_a(c)
        ushort* wa = (c & 1) ? pa1 : pa0;
#pragma unroll
        for (int nb = 0; nb < 4; ++nb) {
            float a0 = fast_exp2(fmaf(Sa[nb][0], k1, b4[nb][0]));
            float a1 = fast_exp2(fmaf(Sa[nb][1], k1, b4[nb][1]));
            float a2 = fast_exp2(fmaf(Sa[nb][2], k1, b4[nb][2]));
            float a3 = fast_exp2(fmaf(Sa[nb][3], k1, b4[nb][3]));
            rsa[0] += a0; rsa[1] += a1; rsa[2] += a2; rsa[3] += a3;
            uint2v pk; pk[0] = packbf2(a0, a1); pk[1] = packbf2(a2, a3);
            *(uint2v*)(wa + nb * 16 + g * 4) = pk;
        }

        // S_b(c): last consumer of kf(c)
#pragma unroll
        for (int nb = 0; nb < 4; ++nb) {
            float4v z = float4v{0.f,0.f,0.f,0.f};
            Sb[nb] = __builtin_amdgcn_mfma_f32_16x16x32_bf16(kf[nb], qfb, z, 0, 0, 0);
        }
        // prefetch K chunk c+1 (WAR clear: S_b issued; at c=15 reads past
        // k_ws into vt_ws -> in-workspace, never consumed)
#pragma unroll
        for (int nb = 0; nb < 4; ++nb)
            kf[nb] = *(const short8*)(kp + (size_t)nb * 16 * HD_);
        kp += (size_t)64 * HD_;

        // PV_b(c-1): last consumer of vf(c-1)
        const ushort* rb = (c & 1) ? pb0 : pb1;
#pragma unroll
        for (int kb = 0; kb < 2; ++kb) {
            short8 bf = *(const short8*)(rb + kb * 32 + g * 8);
            Ob[0] = __builtin_amdgcn_mfma_f32_16x16x32_bf16(bf, vf[kb][0], Ob[0], 0, 0, 0);
            Ob[1] = __builtin_amdgcn_mfma_f32_16x16x32_bf16(bf, vf[kb][1], Ob[1], 0, 0, 0);
        }
        // prefetch V chunk c (WAR clear: both PVs issued)
#pragma unroll
        for (int kb = 0; kb < 2; ++kb)
#pragma unroll
            for (int db = 0; db < 2; ++db)
                vf[kb][db] = *(const short8*)(vp + (size_t)db * 16 * L_ + kb * 32);
        vp += 64;

        // PIN: kf/vf prefetches cannot sink below; softmax_b cannot hoist
        // above.  With waves_per_eu(4,4) the regs stay allocated (no spill).
        __builtin_amdgcn_sched_barrier(0);

        // softmax_b(c)
        ushort* wb = (c & 1) ? pb1 : pb0;
#pragma unroll
        for (int nb = 0; nb < 4; ++nb) {
            float e0 = fast_exp2(fmaf(Sb[nb][0], k1, b4[nb][0]));
            float e1 = fast_exp2(fmaf(Sb[nb][1], k1, b4[nb][1]));
            float e2 = fast_exp2(fmaf(Sb[nb][2], k1, b4[nb][2]));
            float e3 = fast_exp2(fmaf(Sb[nb][3], k1, b4[nb][3]));
            rsb[0] += e0; rsb[1] += e1; rsb[2] += e2; rsb[3] += e3;
            uint2v qk; qk[0] = packbf2(e0, e1); qk[1] = packbf2(e2, e3);
            *(uint2v*)(wb + nb * 16 + g * 4) = qk;
        }
    }

    // ---- epilogue: PV(15) with resident vf; c=15 wrote buf1 ----
#pragma unroll
    for (int kb = 0; kb < 2; ++kb) {
        short8 af = *(const short8*)(pa1 + kb * 32 + g * 8);
        Oa[0] = __builtin_amdgcn_mfma_f32_16x16x32_bf16(af, vf[kb][0], Oa[0], 0, 0, 0);
        Oa[1] = __builtin_amdgcn_mfma_f32_16x16x32_bf16(af, vf[kb][1], Oa[1], 0, 0, 0);
    }
#pragma unroll
    for (int kb = 0; kb < 2; ++kb) {
        short8 bf = *(const short8*)(pb1 + kb * 32 + g * 8);
        Ob[0] = __builtin_amdgcn_mfma_f32_16x16x32_bf16(bf, vf[kb][0], Ob[0], 0, 0, 0);
        Ob[1] = __builtin_amdgcn_mfma_f32_16x16x32_bf16(bf, vf[kb][1], Ob[1], 0, 0, 0);
    }

    float ra = (rsa[0] + rsa[1]) + (rsa[2] + rsa[3]);
    float rb = (rsb[0] + rsb[1]) + (rsb[2] + rsb[3]);
    ra += __shfl_xor(ra, 16, 64); ra += __shfl_xor(ra, 32, 64);
    rb += __shfl_xor(rb, 16, 64); rb += __shfl_xor(rb, 32, 64);
#pragma unroll
    for (int r = 0; r < 4; ++r) {
        float inva = 1.f / __shfl(ra, g * 4 + r, 64);
        float invb = 1.f / __shfl(rb, g * 4 + r, 64);
        size_t rowa = (size_t)n * L_ + q0 + wave * 16 + g * 4 + r;
        size_t rowb = rowa + 64;
#pragma unroll
        for (int db = 0; db < 2; ++db) {
            x_ws[rowa * E_ + h * HD_ + db * 16 + m] = f2b(Oa[db][r] * inva);
            x_ws[rowb * E_ + h * HD_ + db * 16 + m] = f2b(Ob[db][r] * invb);
        }
    }
}

// ---------------------------------------------------------------------------
// Kernel 3: C = X(bf16) @ Wo^T(bf16, pre-converted by proj) + bo, fp32 out.
// UNCHANGED (control).  64x64 tile, BK=64, 1024 blocks, XCD-swizzled,
// register-prefetch pipeline.
// ---------------------------------------------------------------------------
__global__ __launch_bounds__(256) void out_gemm_kernel(
    const ushort* __restrict__ X, const ushort* __restrict__ wo_bf,
    const float* __restrict__ bo, float* __restrict__ C)
{
    const int B = blockIdx.x;
    const int it = ((B >> 7) << 3) + (B & 7);   // 0..63
    const int jt = (B >> 3) & 15;               // 0..15
    const int i0 = it * 64, j0 = jt * 64;

    const int t = threadIdx.x, wave = t >> 6, lane = t & 63;
    const int m = lane & 15, g = lane >> 4;

    __shared__ ushort sA[64][72];
    __shared__ ushort sB[64][72];

    float4v acc[4];
#pragma unroll
    for (int nb = 0; nb < 4; ++nb) acc[nb] = float4v{0.f,0.f,0.f,0.f};

    const int r0 = t >> 2;          // 0..63
    const int c0 = (t & 3) * 16;    // 0..48

    const ushort* xp = X + (size_t)(i0 + r0) * E_ + c0;
    const ushort* wp = wo_bf + (size_t)(j0 + r0) * E_ + c0;

    short8 xr0 = *(const short8*)xp;
    short8 xr1 = *(const short8*)(xp + 8);
    short8 wr0 = *(const short8*)wp;
    short8 wr1 = *(const short8*)(wp + 8);

    for (int k0 = 0; k0 < E_; k0 += 64) {
        __syncthreads();
        *(short8*)&sA[r0][c0]     = xr0;
        *(short8*)&sA[r0][c0 + 8] = xr1;
        *(short8*)&sB[r0][c0]     = wr0;
        *(short8*)&sB[r0][c0 + 8] = wr1;
        __syncthreads();
        if (k0 + 64 < E_) {   // uniform; prefetch next k-tile during compute
            xr0 = *(const short8*)(xp + k0 + 64);
            xr1 = *(const short8*)(xp + k0 + 72);
            wr0 = *(const short8*)(wp + k0 + 64);
            wr1 = *(const short8*)(wp + k0 + 72);
        }
#pragma unroll
        for (int kb = 0; kb < 2; ++kb) {
            short8 afr = *(const short8*)&sA[wave * 16 + m][kb * 32 + g * 8];
#pragma unroll
            for (int nb = 0; nb < 4; ++nb) {
                short8 bfr = *(const short8*)&sB[nb * 16 + m][kb * 32 + g * 8];
                acc[nb] = __builtin_amdgcn_mfma_f32_16x16x32_bf16(afr, bfr, acc[nb], 0, 0, 0);
            }
        }
    }

#pragma unroll
    for (int nb = 0; nb < 4; ++nb) {
        int col = j0 + nb * 16 + m;
        float bias = bo[col];
#pragma unroll
        for (int r = 0; r < 4; ++r) {
            int rowi = i0 + wave * 16 + g * 4 + r;
            C[(size_t)rowi * E_ + col] = acc[nb][r] + bias;
        }
    }
}

// ---------------------------------------------------------------------------
extern "C" void kernel_launch(void* const* d_in, const int* in_sizes, int n_in,
                              void* d_out, int out_size, void* d_ws, size_t ws_size,
                              hipStream_t stream) {
    const float* values = (const float*)d_in[0];
    const float* keys   = (const float*)d_in[1];
    const float* query  = (const float*)d_in[2];
    const int*   mask   = (const int*)d_in[3];
    const float* Wv     = (const float*)d_in[4];
    const float* Wk     = (const float*)d_in[5];
    const float* Wq     = (const float*)d_in[6];
    const float* Wo     = (const float*)d_in[7];
    const float* bo     = (const float*)d_in[8];
    float* out = (float*)d_out;

    const size_t M4 = (size_t)N_ * H_ * L_ * HD_;   // 4 Mi elements
    ushort* q_ws   = (ushort*)d_ws;
    ushort* k_ws   = q_ws + M4;
    ushort* vt_ws  = k_ws + M4;
    ushort* x_ws   = vt_ws + M4;
    ushort* wo_bf  = x_ws + M4;                     // 1 Mi ushort
    float*  bias_f = (float*)(wo_bf + (size_t)E_ * E_);  // 4096 floats

    proj_kernel<<<dim3(L_ / 64, H_, N_), 256, 0, stream>>>(
        values, keys, query, Wv, Wk, Wq, Wo, mask,
        vt_ws, k_ws, q_ws, wo_bf, bias_f);

    attn_kernel<<<dim3(1024), 256, 0, stream>>>(
        q_ws, k_ws, vt_ws, bias_f, x_ws);

    out_gemm_kernel<<<dim3(1024), 256, 0, stream>>>(
        x_ws, wo_bf, bo, out);
}

// Round 9
// 178.340 us; speedup vs baseline: 1.1962x; 1.1919x over previous
//
#include <hip/hip_runtime.h>
#include <hip/hip_bf16.h>

#define N_ 4
#define L_ 1024
#define E_ 1024
#define H_ 32
#define HD_ 32

typedef unsigned short ushort;
typedef __attribute__((ext_vector_type(8))) short short8;   // bf16 x8 MFMA A/B frag
typedef __attribute__((ext_vector_type(4))) float float4v;  // MFMA C/D frag
typedef __attribute__((ext_vector_type(2))) unsigned int uint2v;
typedef __attribute__((ext_vector_type(2))) float float2v;

// branch-free RNE f32->bf16 (finite inputs)
__device__ __forceinline__ unsigned packbf2(float a, float b) {
    unsigned ua = __float_as_uint(a);
    unsigned ub = __float_as_uint(b);
    ua += 0x7FFFu + ((ua >> 16) & 1u);
    ub += 0x7FFFu + ((ub >> 16) & 1u);
    return (ua >> 16) | (ub & 0xFFFF0000u);
}

__device__ __forceinline__ ushort f2b(float f) {
    unsigned u = __float_as_uint(f);
    u += 0x7FFFu + ((u >> 16) & 1u);
    return (ushort)(u >> 16);
}

__device__ __forceinline__ float fast_exp2(float x) {
#if __has_builtin(__builtin_amdgcn_exp2f)
    return __builtin_amdgcn_exp2f(x);        // raw v_exp_f32 (2^x)
#else
    return __expf(x * 0.69314718056f);
#endif
}

// load 8 consecutive fp32, convert to bf16x8 frag (RNE)
__device__ __forceinline__ short8 cvt8(const float* __restrict__ p) {
    float4v a = *(const float4v*)p;
    float4v b = *(const float4v*)(p + 4);
    union { unsigned u[4]; short8 s; } r;
    r.u[0] = packbf2(a[0], a[1]); r.u[1] = packbf2(a[2], a[3]);
    r.u[2] = packbf2(b[0], b[1]); r.u[3] = packbf2(b[2], b[3]);
    return r.s;
}

// async global->LDS DMA, 16B per lane, LDS dest = wave-uniform base + lane*16
typedef __attribute__((address_space(1))) const unsigned int as1_u32;
typedef __attribute__((address_space(3))) unsigned int as3_u32;
__device__ __forceinline__ void g2l16(const void* gp, void* lp) {
    __builtin_amdgcn_global_load_lds((as1_u32*)gp, (as3_u32*)lp, 16, 0, 0);
}

// ---------------------------------------------------------------------------
// Kernel 1: per-head projections via MFMA, no LDS.  UNCHANGED (control).
// grid (L/64, H, N), block 256.
// ---------------------------------------------------------------------------
__global__ __launch_bounds__(256) void proj_kernel(
    const float* __restrict__ v_in, const float* __restrict__ k_in,
    const float* __restrict__ q_in,
    const float* __restrict__ Wv, const float* __restrict__ Wk,
    const float* __restrict__ Wq, const float* __restrict__ Wo,
    const int* __restrict__ mask,
    ushort* __restrict__ vt_ws, ushort* __restrict__ k_ws,
    ushort* __restrict__ q_ws, ushort* __restrict__ wo_bf,
    float* __restrict__ bias_f)
{
    const int n = blockIdx.z, h = blockIdx.y, l0 = blockIdx.x * 64;
    const int t = threadIdx.x, wave = t >> 6, lane = t & 63;
    const int m = lane & 15, g = lane >> 4;

    // Wo -> bf16: linear block id covers 1Mi elements, 2 per thread
    {
        const int lb = ((n * H_ + h) << 4) + blockIdx.x;   // 0..2047
        const int i = lb * 256 + t;                        // dword index
        float2v w2 = *(const float2v*)(Wo + 2 * i);
        ((unsigned*)wo_bf)[i] = packbf2(w2[0], w2[1]);
    }
    // mask -> additive bias, done once (h==0 slice)
    if (h == 0 && t < 64)
        bias_f[n * L_ + l0 + t] = (mask[n * L_ + l0 + t] == 0) ? -1e30f : 0.0f;

    const size_t row = (size_t)(n * L_) + l0 + wave * 16 + m;
    const float* src[3] = {v_in, k_in, q_in};
    const float* wsrc[3] = {Wv, Wk, Wq};

    short8 Xf[3], Wf[3][2];
#pragma unroll
    for (int mat = 0; mat < 3; ++mat) {
        Xf[mat] = cvt8(src[mat] + row * E_ + h * HD_ + g * 8);
#pragma unroll
        for (int dt = 0; dt < 2; ++dt)
            Wf[mat][dt] = cvt8(wsrc[mat] + (dt * 16 + m) * HD_ + g * 8);
    }

    const size_t obase = (size_t)(n * H_ + h) * L_;
    const size_t vb = (size_t)(n * H_ + h) * HD_ * L_;
    const int tok = l0 + wave * 16 + m;   // this lane's token (D col = m)

    // q,k: D[d][tok]; lane's 4 accs are consecutive d -> one 8B store per dt
#pragma unroll
    for (int mat = 1; mat < 3; ++mat) {
        ushort* outp = (mat == 1) ? k_ws : q_ws;
#pragma unroll
        for (int dt = 0; dt < 2; ++dt) {
            float4v z = float4v{0.f, 0.f, 0.f, 0.f};
            float4v acc = __builtin_amdgcn_mfma_f32_16x16x32_bf16(Wf[mat][dt], Xf[mat], z, 0, 0, 0);
            uint2v pk;
            pk[0] = packbf2(acc[0], acc[1]);
            pk[1] = packbf2(acc[2], acc[3]);
            *(uint2v*)(outp + (obase + tok) * HD_ + dt * 16 + g * 4) = pk;
        }
    }
    // v: D[d][tok] -> vt[d][tok], lane m = tok (coalesced 32B runs)
#pragma unroll
    for (int dt = 0; dt < 2; ++dt) {
        float4v z = float4v{0.f, 0.f, 0.f, 0.f};
        float4v acc = __builtin_amdgcn_mfma_f32_16x16x32_bf16(Wf[0][dt], Xf[0], z, 0, 0, 0);
#pragma unroll
        for (int r = 0; r < 4; ++r) {
            int d = dt * 16 + g * 4 + r;
            vt_ws[vb + (size_t)d * L_ + tok] = f2b(acc[r]);
        }
    }
}

// ---------------------------------------------------------------------------
// Kernel 2: attention — round-8's global_load_lds K/V staging (verified sync
// math) + rounds-0-7's KNOWN-GOOD P-LDS path and epilogue (r8's bpermute
// transpose had a source-vs-dest select bug; reverted).  PV runs in the same
// chunk as softmax (staging dbuf provides overlap) so sP needs no double
// buffer: 18KB.  Bias staged to LDS once -> no in-loop global loads, so the
// counted vmcnt(2) is never drained by compiler-inserted waits.
// LDS: sK 8KB + sV 8KB + sP 18KB + sBias 4KB = 38.9KB -> 4 blocks/CU.
// grid 1024 blocks, block 256, 2 barriers/chunk, vmcnt(2) never 0 till end.
// ---------------------------------------------------------------------------
__global__ __launch_bounds__(256, 4) void attn_kernel(
    const ushort* __restrict__ q_ws, const ushort* __restrict__ k_ws,
    const ushort* __restrict__ vt_ws, const float* __restrict__ bias_f,
    ushort* __restrict__ x_ws)
{
    const int B = blockIdx.x;
    const int head = ((B >> 6) << 3) + (B & 7);   // same-head blocks ≡ mod 8 -> same XCD
    const int qt = (B >> 3) & 7;
    const int n = head >> 5, h = head & 31, q0 = qt * 128;

    const int t = threadIdx.x, wave = t >> 6, lane = t & 63;
    const int m = lane & 15, g = lane >> 4;

    __shared__ ushort sK[2][64][32];     // [buf][tok][d]          4KB/buf
    __shared__ ushort sV[2][32][64];     // [buf][d][tok] swizzled 4KB/buf
    __shared__ ushort sP[4][2][16][72];  // [wave][tile][q][tok]   18KB
    __shared__ float  sB4[L_];           // bias row for this n    4KB

    const size_t base = (size_t)(n * H_ + h) * L_;
    const ushort* vtb = vt_ws + (size_t)(n * H_ + h) * HD_ * L_;

    // Q fragments + bias->LDS FIRST (compiler-managed waits happen before
    // any DMA is outstanding)
    short8 qfa = *(const short8*)(q_ws + (base + q0 + wave * 16 + m) * HD_ + g * 8);
    short8 qfb = *(const short8*)(q_ws + (base + q0 + 64 + wave * 16 + m) * HD_ + g * 8);
    {
        float4v b = *(const float4v*)(bias_f + n * L_ + t * 4);
        *(float4v*)&sB4[t * 4] = b;
    }

    // staging source addresses (16B per lane)
    const ushort* kgp = k_ws + base * HD_ + (size_t)t * 8;          // linear copy
    const ushort* vgp = vtb + (size_t)(t >> 3) * L_
                            + (((t & 7) ^ ((t >> 3) & 7)) << 3);    // inverse-swizzled src

    // stage chunks 0 and 1 (order: K0,V0,K1,V1 -> vmcnt(2) retires set 0)
    g2l16(kgp,             &sK[0][wave * 16][0]);
    g2l16(vgp,             &sV[0][wave * 8][0]);
    g2l16(kgp + 64 * HD_,  &sK[1][wave * 16][0]);
    g2l16(vgp + 64,        &sV[1][wave * 8][0]);

    // own bias ds_writes retired before the collective barrier in chunk 0
    asm volatile("s_waitcnt lgkmcnt(0)" ::: "memory");

    float4v Oa[2], Ob[2];
    Oa[0] = float4v{0.f,0.f,0.f,0.f}; Oa[1] = float4v{0.f,0.f,0.f,0.f};
    Ob[0] = float4v{0.f,0.f,0.f,0.f}; Ob[1] = float4v{0.f,0.f,0.f,0.f};
    float rsa[4] = {0.f,0.f,0.f,0.f}, rsb[4] = {0.f,0.f,0.f,0.f};
    const float k1 = 0.03125f * 1.44269504f;

    ushort* const pa = &sP[wave][0][m][0];
    ushort* const pb = &sP[wave][1][m][0];
    const int xsw = (m & 7) << 3;   // V read swizzle (elements)

    for (int c = 0; c < 16; ++c) {
        const int buf = c & 1;

        // chunk c's DMA retired; chunk c+1's 2 loads stay in flight
        if (c < 15) asm volatile("s_waitcnt vmcnt(2)" ::: "memory");
        else        asm volatile("s_waitcnt vmcnt(0)" ::: "memory");
        __builtin_amdgcn_s_barrier();

        // K fragments from LDS (balanced banks: 8 dw/bank = b128 floor)
        short8 kf[4];
#pragma unroll
        for (int nb = 0; nb < 4; ++nb)
            kf[nb] = *(const short8*)&sK[buf][nb * 16 + m][g * 8];

        float4v Sa[4], Sb[4];
#pragma unroll
        for (int nb = 0; nb < 4; ++nb) {
            float4v z = float4v{0.f,0.f,0.f,0.f};
            Sa[nb] = __builtin_amdgcn_mfma_f32_16x16x32_bf16(kf[nb], qfa, z, 0, 0, 0);
            Sb[nb] = __builtin_amdgcn_mfma_f32_16x16x32_bf16(kf[nb], qfb, z, 0, 0, 0);
        }

        // bias from LDS (broadcast reads)
        float4v b4[4];
#pragma unroll
        for (int nb = 0; nb < 4; ++nb)
            b4[nb] = *(const float4v*)&sB4[c * 64 + nb * 16 + g * 4];

        // V^T fragments from LDS (XOR-swizzled, balanced banks)
        short8 vf[2][2];
#pragma unroll
        for (int kb = 0; kb < 2; ++kb)
#pragma unroll
            for (int db = 0; db < 2; ++db)
                vf[kb][db] = *(const short8*)
                    &sV[buf][db * 16 + m][(kb * 32 + g * 8) ^ xsw];

        // ---- tile a: softmax -> sP tile0 -> PV (rounds-0-7 path) ----
#pragma unroll
        for (int nb = 0; nb < 4; ++nb) {
            float a0 = fast_exp2(fmaf(Sa[nb][0], k1, b4[nb][0]));
            float a1 = fast_exp2(fmaf(Sa[nb][1], k1, b4[nb][1]));
            float a2 = fast_exp2(fmaf(Sa[nb][2], k1, b4[nb][2]));
            float a3 = fast_exp2(fmaf(Sa[nb][3], k1, b4[nb][3]));
            rsa[0] += a0; rsa[1] += a1; rsa[2] += a2; rsa[3] += a3;
            uint2v pk; pk[0] = packbf2(a0, a1); pk[1] = packbf2(a2, a3);
            *(uint2v*)(pa + nb * 16 + g * 4) = pk;
        }
#pragma unroll
        for (int kb = 0; kb < 2; ++kb) {
            short8 af = *(const short8*)(pa + kb * 32 + g * 8);
            Oa[0] = __builtin_amdgcn_mfma_f32_16x16x32_bf16(af, vf[kb][0], Oa[0], 0, 0, 0);
            Oa[1] = __builtin_amdgcn_mfma_f32_16x16x32_bf16(af, vf[kb][1], Oa[1], 0, 0, 0);
        }

        // ---- tile b ----
#pragma unroll
        for (int nb = 0; nb < 4; ++nb) {
            float e0 = fast_exp2(fmaf(Sb[nb][0], k1, b4[nb][0]));
            float e1 = fast_exp2(fmaf(Sb[nb][1], k1, b4[nb][1]));
            float e2 = fast_exp2(fmaf(Sb[nb][2], k1, b4[nb][2]));
            float e3 = fast_exp2(fmaf(Sb[nb][3], k1, b4[nb][3]));
            rsb[0] += e0; rsb[1] += e1; rsb[2] += e2; rsb[3] += e3;
            uint2v pk; pk[0] = packbf2(e0, e1); pk[1] = packbf2(e2, e3);
            *(uint2v*)(pb + nb * 16 + g * 4) = pk;
        }
#pragma unroll
        for (int kb = 0; kb < 2; ++kb) {
            short8 bf = *(const short8*)(pb + kb * 32 + g * 8);
            Ob[0] = __builtin_amdgcn_mfma_f32_16x16x32_bf16(bf, vf[kb][0], Ob[0], 0, 0, 0);
            Ob[1] = __builtin_amdgcn_mfma_f32_16x16x32_bf16(bf, vf[kb][1], Ob[1], 0, 0, 0);
        }

        // all waves done reading buf -> safe to overwrite with chunk c+2
        if (c < 14) {
            __builtin_amdgcn_s_barrier();
            __builtin_amdgcn_sched_barrier(0);
            g2l16(kgp + (size_t)(c + 2) * 64 * HD_, &sK[buf][wave * 16][0]);
            g2l16(vgp + (c + 2) * 64,               &sV[buf][wave * 8][0]);
        }
    }

    // ---- epilogue: rounds-0-7 form (O[q=g*4+r][d=db*16+m]) ----
    float ra = (rsa[0] + rsa[1]) + (rsa[2] + rsa[3]);
    float rb = (rsb[0] + rsb[1]) + (rsb[2] + rsb[3]);
    ra += __shfl_xor(ra, 16, 64); ra += __shfl_xor(ra, 32, 64);
    rb += __shfl_xor(rb, 16, 64); rb += __shfl_xor(rb, 32, 64);
#pragma unroll
    for (int r = 0; r < 4; ++r) {
        float inva = 1.f / __shfl(ra, g * 4 + r, 64);
        float invb = 1.f / __shfl(rb, g * 4 + r, 64);
        size_t rowa = (size_t)n * L_ + q0 + wave * 16 + g * 4 + r;
        size_t rowb = rowa + 64;
#pragma unroll
        for (int db = 0; db < 2; ++db) {
            x_ws[rowa * E_ + h * HD_ + db * 16 + m] = f2b(Oa[db][r] * inva);
            x_ws[rowb * E_ + h * HD_ + db * 16 + m] = f2b(Ob[db][r] * invb);
        }
    }
}

// ---------------------------------------------------------------------------
// Kernel 3: C = X(bf16) @ Wo^T(bf16, pre-converted by proj) + bo, fp32 out.
// UNCHANGED (control).  64x64 tile, BK=64, 1024 blocks, XCD-swizzled,
// register-prefetch pipeline.
// ---------------------------------------------------------------------------
__global__ __launch_bounds__(256) void out_gemm_kernel(
    const ushort* __restrict__ X, const ushort* __restrict__ wo_bf,
    const float* __restrict__ bo, float* __restrict__ C)
{
    const int B = blockIdx.x;
    const int it = ((B >> 7) << 3) + (B & 7);   // 0..63
    const int jt = (B >> 3) & 15;               // 0..15
    const int i0 = it * 64, j0 = jt * 64;

    const int t = threadIdx.x, wave = t >> 6, lane = t & 63;
    const int m = lane & 15, g = lane >> 4;

    __shared__ ushort sA[64][72];
    __shared__ ushort sB[64][72];

    float4v acc[4];
#pragma unroll
    for (int nb = 0; nb < 4; ++nb) acc[nb] = float4v{0.f,0.f,0.f,0.f};

    const int r0 = t >> 2;          // 0..63
    const int c0 = (t & 3) * 16;    // 0..48

    const ushort* xp = X + (size_t)(i0 + r0) * E_ + c0;
    const ushort* wp = wo_bf + (size_t)(j0 + r0) * E_ + c0;

    short8 xr0 = *(const short8*)xp;
    short8 xr1 = *(const short8*)(xp + 8);
    short8 wr0 = *(const short8*)wp;
    short8 wr1 = *(const short8*)(wp + 8);

    for (int k0 = 0; k0 < E_; k0 += 64) {
        __syncthreads();
        *(short8*)&sA[r0][c0]     = xr0;
        *(short8*)&sA[r0][c0 + 8] = xr1;
        *(short8*)&sB[r0][c0]     = wr0;
        *(short8*)&sB[r0][c0 + 8] = wr1;
        __syncthreads();
        if (k0 + 64 < E_) {   // uniform; prefetch next k-tile during compute
            xr0 = *(const short8*)(xp + k0 + 64);
            xr1 = *(const short8*)(xp + k0 + 72);
            wr0 = *(const short8*)(wp + k0 + 64);
            wr1 = *(const short8*)(wp + k0 + 72);
        }
#pragma unroll
        for (int kb = 0; kb < 2; ++kb) {
            short8 afr = *(const short8*)&sA[wave * 16 + m][kb * 32 + g * 8];
#pragma unroll
            for (int nb = 0; nb < 4; ++nb) {
                short8 bfr = *(const short8*)&sB[nb * 16 + m][kb * 32 + g * 8];
                acc[nb] = __builtin_amdgcn_mfma_f32_16x16x32_bf16(afr, bfr, acc[nb], 0, 0, 0);
            }
        }
    }

#pragma unroll
    for (int nb = 0; nb < 4; ++nb) {
        int col = j0 + nb * 16 + m;
        float bias = bo[col];
#pragma unroll
        for (int r = 0; r < 4; ++r) {
            int rowi = i0 + wave * 16 + g * 4 + r;
            C[(size_t)rowi * E_ + col] = acc[nb][r] + bias;
        }
    }
}

// ---------------------------------------------------------------------------
extern "C" void kernel_launch(void* const* d_in, const int* in_sizes, int n_in,
                              void* d_out, int out_size, void* d_ws, size_t ws_size,
                              hipStream_t stream) {
    const float* values = (const float*)d_in[0];
    const float* keys   = (const float*)d_in[1];
    const float* query  = (const float*)d_in[2];
    const int*   mask   = (const int*)d_in[3];
    const float* Wv     = (const float*)d_in[4];
    const float* Wk     = (const float*)d_in[5];
    const float* Wq     = (const float*)d_in[6];
    const float* Wo     = (const float*)d_in[7];
    const float* bo     = (const float*)d_in[8];
    float* out = (float*)d_out;

    const size_t M4 = (size_t)N_ * H_ * L_ * HD_;   // 4 Mi elements
    ushort* q_ws   = (ushort*)d_ws;
    ushort* k_ws   = q_ws + M4;
    ushort* vt_ws  = k_ws + M4;
    ushort* x_ws   = vt_ws + M4;
    ushort* wo_bf  = x_ws + M4;                     // 1 Mi ushort
    float*  bias_f = (float*)(wo_bf + (size_t)E_ * E_);  // 4096 floats

    proj_kernel<<<dim3(L_ / 64, H_, N_), 256, 0, stream>>>(
        values, keys, query, Wv, Wk, Wq, Wo, mask,
        vt_ws, k_ws, q_ws, wo_bf, bias_f);

    attn_kernel<<<dim3(1024), 256, 0, stream>>>(
        q_ws, k_ws, vt_ws, bias_f, x_ws);

    out_gemm_kernel<<<dim3(1024), 256, 0, stream>>>(
        x_ws, wo_bf, bo, out);
}